// Round 9
// baseline (260.496 us; speedup 1.0000x reference)
//
#include <hip/hip_runtime.h>
#include <hip/hip_bf16.h>

#define B 6
#define S 1024
#define H 12
#define DK 64
#define DM 768
#define M (B*S)      // 6144
#define BH (B*H)     // 72

typedef __bf16 bf16;
typedef __attribute__((ext_vector_type(8))) __bf16 bf16x8;
typedef __attribute__((ext_vector_type(4))) float f32x4;

#define MFMA __builtin_amdgcn_mfma_f32_16x16x32_bf16
#define SFENCE() __builtin_amdgcn_sched_barrier(0)
#define WAITV(N) asm volatile("s_waitcnt vmcnt(" #N ")" ::: "memory")
#define BARRIER() __builtin_amdgcn_s_barrier()

// async global->LDS, 16B per lane; LDS dst = wave-uniform base + lane*16
__device__ __forceinline__ void gl16(const void* g, void* l) {
  __builtin_amdgcn_global_load_lds(
      (const __attribute__((address_space(1))) unsigned int*)g,
      (__attribute__((address_space(3))) unsigned int*)l, 16, 0, 0);
}

// ---------------- prep: input f32->bf16 convert (z<3) + weight transpose (z>=3)
__global__ void k_prep(const float* __restrict__ Q, const float* __restrict__ K,
                       const float* __restrict__ V,
                       const float* __restrict__ Wq, const float* __restrict__ Wk,
                       const float* __restrict__ Wv, const float* __restrict__ Wo,
                       bf16* __restrict__ xb, bf16* __restrict__ wt) {
  int z = blockIdx.y;
  if (z < 3) {
    const float* X = z==0?Q : z==1?K : V;
    size_t i = ((size_t)blockIdx.x*256 + threadIdx.x)*8;
    float4 a = *(const float4*)(X + i);
    float4 b = *(const float4*)(X + i + 4);
    bf16x8 r;
    r[0]=(bf16)a.x; r[1]=(bf16)a.y; r[2]=(bf16)a.z; r[3]=(bf16)a.w;
    r[4]=(bf16)b.x; r[5]=(bf16)b.y; r[6]=(bf16)b.z; r[7]=(bf16)b.w;
    *(bf16x8*)(xb + (size_t)z*M*DM + i) = r;
  } else {
    int zz = z - 3;
    const float* W = zz==0?Wq : zz==1?Wk : zz==2?Wv : Wo;
    int idx = blockIdx.x*256 + threadIdx.x;   // 0..768*768-1
    int k = idx / DM, n = idx % DM;
    wt[(size_t)zz*DM*DM + (size_t)n*DM + k] = (bf16)W[idx];
  }
}

// ======== GEMM bodies: 128x128 tile, BK=32, 3-deep LDS via global_load_lds ====
// LDS tile [128 rows][4 chunks of 16B]; chunk c holds source chunk c^((row>>1)&3).
// gl16 dst is linear (base + lane*16); swizzle pre-applied on the global source.

// ---------------- QKV projection; epilogue scatters q/k/v (kb,vt pre-swizzled)
__global__ __launch_bounds__(256, 3) void k_proj(
    const bf16* __restrict__ xb, const bf16* __restrict__ wt,
    const float* __restrict__ bq, const float* __restrict__ bk,
    const float* __restrict__ bv,
    bf16* __restrict__ qb, bf16* __restrict__ kb, bf16* __restrict__ vt) {
  int z = blockIdx.z;
  const bf16* X    = xb + (size_t)z*M*DM;
  const float* bias = z==0?bq : z==1?bk : bv;
  const bf16* Wt = wt + (size_t)z*DM*DM;
  int tid = threadIdx.x, lane = tid & 63, w = tid >> 6;
  int wr = w >> 1, wc = w & 1;
  int lr = lane & 15, lg = lane >> 4;
  int m0 = blockIdx.x*128;
  int n0 = blockIdx.y*128;

  __shared__ bf16 As[3][4096];
  __shared__ bf16 Bs[3][4096];
  char* AsL = (char*)&As[0][0];
  char* BsL = (char*)&Bs[0][0];

  // staging: chunk d1 = tid (rows 0..63), d2 = tid+256 (rows 64..127)
  const int r1 = tid >> 2, p1 = tid & 3;
  const int s1 = p1 ^ ((r1 >> 1) & 3);      // same for r2 = r1+64
  const bf16* a1 = X  + (size_t)(m0 + r1)*DM      + s1*8;
  const bf16* a2 = X  + (size_t)(m0 + r1 + 64)*DM + s1*8;
  const bf16* b1 = Wt + (size_t)(n0 + r1)*DM      + s1*8;
  const bf16* b2 = Wt + (size_t)(n0 + r1 + 64)*DM + s1*8;
  const int ldsOff = w*1024;                // + buf*8192 (+4096 for d2)

  const int fs = (lr >> 1) & 3;
  const int fchunk = (lg ^ fs) * 8;

  f32x4 acc[4][4];
  #pragma unroll
  for (int i=0;i<4;++i)
    #pragma unroll
    for (int j=0;j<4;++j) acc[i][j] = (f32x4){0.f,0.f,0.f,0.f};

  // prologue: stage tiles 0,1
  #pragma unroll
  for (int tt = 0; tt < 2; ++tt) {
    gl16(a1 + tt*32, AsL + tt*8192 + ldsOff);
    gl16(a2 + tt*32, AsL + tt*8192 + 4096 + ldsOff);
    gl16(b1 + tt*32, BsL + tt*8192 + ldsOff);
    gl16(b2 + tt*32, BsL + tt*8192 + 4096 + ldsOff);
  }
  SFENCE();
  WAITV(4);      // L(0) done (L(1)'s 4 may remain)
  BARRIER();
  SFENCE();

  int cur = 0, nb = 2;
  for (int t = 0; t < 24; ++t) {
    const bf16* Ac = (const bf16*)(AsL + cur*8192);
    const bf16* Bc = (const bf16*)(BsL + cur*8192);
    if (t < 22) {
      int k0 = (t+2)*32;
      gl16(a1 + k0, AsL + nb*8192 + ldsOff);
      gl16(a2 + k0, AsL + nb*8192 + 4096 + ldsOff);
      gl16(b1 + k0, BsL + nb*8192 + ldsOff);
      gl16(b2 + k0, BsL + nb*8192 + 4096 + ldsOff);
    }
    SFENCE();
    bf16x8 af[4], bfr[4];
    __builtin_amdgcn_s_setprio(1);
    #pragma unroll
    for (int mi=0;mi<4;++mi) af[mi]  = *(const bf16x8*)&Ac[(wr*64 + mi*16 + lr)*32 + fchunk];
    #pragma unroll
    for (int ni=0;ni<4;++ni) bfr[ni] = *(const bf16x8*)&Bc[(wc*64 + ni*16 + lr)*32 + fchunk];
    #pragma unroll
    for (int mi=0;mi<4;++mi)
      #pragma unroll
      for (int ni=0;ni<4;++ni)
        acc[mi][ni] = MFMA(af[mi], bfr[ni], acc[mi][ni], 0,0,0);
    __builtin_amdgcn_s_setprio(0);
    SFENCE();
    if (t < 23) {
      if (t < 22) { WAITV(4); } else { WAITV(0); }
      BARRIER();
      SFENCE();
    }
    cur = (cur==2)?0:cur+1;
    nb  = (nb==2)?0:nb+1;
  }

  int mw = m0 + wr*64, nw = n0 + wc*64;
  #pragma unroll
  for (int ni=0;ni<4;++ni) {
    int n = nw + ni*16 + lr;
    float bs = bias[n];
    int h = n >> 6, d = n & 63;
    #pragma unroll
    for (int mi=0;mi<4;++mi)
      #pragma unroll
      for (int r=0;r<4;++r) {
        int m = mw + mi*16 + lg*4 + r;
        int bb = m >> 10, s = m & 1023;
        float val = acc[mi][ni][r] + bs;
        if (z == 0) {
          qb[((size_t)(bb*H + h)*S + s)*DK + d] = (bf16)val;
        } else if (z == 1) {
          int dsw = ((((d>>3) ^ (s&7))) << 3) | (d&7);          // slot ^= s&7
          kb[((size_t)(bb*H + h)*S + s)*DK + dsw] = (bf16)val;
        } else {
          int ssw = (s & ~63) | ((((s&63)>>3) ^ (d&7)) << 3) | (s&7); // slot ^= d&7
          vt[((size_t)(bb*H + h)*DK + d)*S + ssw] = (bf16)val;
        }
      }
  }
}

// ---------------- out projection + bias + residual -> x (f32), same tiled body
__global__ __launch_bounds__(256, 3) void k_oproj(
    const bf16* __restrict__ ctx, const bf16* __restrict__ wto,
    const float* __restrict__ bo, const float* __restrict__ res,
    float* __restrict__ x) {
  int tid = threadIdx.x, lane = tid & 63, w = tid >> 6;
  int wr = w >> 1, wc = w & 1;
  int lr = lane & 15, lg = lane >> 4;
  int m0 = blockIdx.x*128;
  int n0 = blockIdx.y*128;

  __shared__ bf16 As[3][4096];
  __shared__ bf16 Bs[3][4096];
  char* AsL = (char*)&As[0][0];
  char* BsL = (char*)&Bs[0][0];

  const int r1 = tid >> 2, p1 = tid & 3;
  const int s1 = p1 ^ ((r1 >> 1) & 3);
  const bf16* a1 = ctx + (size_t)(m0 + r1)*DM      + s1*8;
  const bf16* a2 = ctx + (size_t)(m0 + r1 + 64)*DM + s1*8;
  const bf16* b1 = wto + (size_t)(n0 + r1)*DM      + s1*8;
  const bf16* b2 = wto + (size_t)(n0 + r1 + 64)*DM + s1*8;
  const int ldsOff = w*1024;

  const int fs = (lr >> 1) & 3;
  const int fchunk = (lg ^ fs) * 8;

  f32x4 acc[4][4];
  #pragma unroll
  for (int i=0;i<4;++i)
    #pragma unroll
    for (int j=0;j<4;++j) acc[i][j] = (f32x4){0.f,0.f,0.f,0.f};

  #pragma unroll
  for (int tt = 0; tt < 2; ++tt) {
    gl16(a1 + tt*32, AsL + tt*8192 + ldsOff);
    gl16(a2 + tt*32, AsL + tt*8192 + 4096 + ldsOff);
    gl16(b1 + tt*32, BsL + tt*8192 + ldsOff);
    gl16(b2 + tt*32, BsL + tt*8192 + 4096 + ldsOff);
  }
  SFENCE();
  WAITV(4);
  BARRIER();
  SFENCE();

  int cur = 0, nb = 2;
  for (int t = 0; t < 24; ++t) {
    const bf16* Ac = (const bf16*)(AsL + cur*8192);
    const bf16* Bc = (const bf16*)(BsL + cur*8192);
    if (t < 22) {
      int k0 = (t+2)*32;
      gl16(a1 + k0, AsL + nb*8192 + ldsOff);
      gl16(a2 + k0, AsL + nb*8192 + 4096 + ldsOff);
      gl16(b1 + k0, BsL + nb*8192 + ldsOff);
      gl16(b2 + k0, BsL + nb*8192 + 4096 + ldsOff);
    }
    SFENCE();
    bf16x8 af[4], bfr[4];
    __builtin_amdgcn_s_setprio(1);
    #pragma unroll
    for (int mi=0;mi<4;++mi) af[mi]  = *(const bf16x8*)&Ac[(wr*64 + mi*16 + lr)*32 + fchunk];
    #pragma unroll
    for (int ni=0;ni<4;++ni) bfr[ni] = *(const bf16x8*)&Bc[(wc*64 + ni*16 + lr)*32 + fchunk];
    #pragma unroll
    for (int mi=0;mi<4;++mi)
      #pragma unroll
      for (int ni=0;ni<4;++ni)
        acc[mi][ni] = MFMA(af[mi], bfr[ni], acc[mi][ni], 0,0,0);
    __builtin_amdgcn_s_setprio(0);
    SFENCE();
    if (t < 23) {
      if (t < 22) { WAITV(4); } else { WAITV(0); }
      BARRIER();
      SFENCE();
    }
    cur = (cur==2)?0:cur+1;
    nb  = (nb==2)?0:nb+1;
  }

  int mw = m0 + wr*64, nw = n0 + wc*64;
  #pragma unroll
  for (int ni=0;ni<4;++ni) {
    int n = nw + ni*16 + lr;
    float bb = bo[n];
    #pragma unroll
    for (int mi=0;mi<4;++mi)
      #pragma unroll
      for (int r=0;r<4;++r) {
        int m = mw + mi*16 + lg*4 + r;
        x[(size_t)m*DM + n] = acc[mi][ni][r] + bb + res[(size_t)m*DM + n];
      }
  }
}

__device__ __forceinline__ unsigned pk2(float a, float b) {
  union { bf16 h[2]; unsigned u; } x;
  x.h[0] = (bf16)a; x.h[1] = (bf16)b;
  return x.u;
}

// ---------------- fused attention: gload_lds double-buffer + counted vmcnt.
// Block = (bh, 64 q-rows), 4 waves x 16 rows. Pass1: row sums; pass2: attn+PV.
// Windows: pass1 vmcnt(4) = 4 mask loads after 2 K-loads;
//          pass2 vmcnt(8) = 4 mask loads + 4 attn stores after 4 K/V-loads.
__global__ __launch_bounds__(256, 4) void k_fattn(
    const bf16* __restrict__ qb, const bf16* __restrict__ kb,
    const bf16* __restrict__ vt, const unsigned char* __restrict__ mask,
    float* __restrict__ attn, bf16* __restrict__ ctx) {
  int lin = blockIdx.x + 16*blockIdx.y;   // 0..1151
  int xcd  = lin & 7;
  int slot = lin >> 3;
  int qt   = slot & 15;
  int bh   = xcd*9 + (slot >> 4);         // bijective remap: head locality per XCD
  int b = bh / H, h = bh - b*H;
  int tid = threadIdx.x, lane = tid & 63, w = tid >> 6;
  int lr = lane & 15, lg = lane >> 4;
  int q0 = qt*64 + w*16;

  __shared__ bf16 Kb[2][4096];      // [64 k][64 dk] swizzled, 8KB each
  __shared__ bf16 Vb[2][4096];      // [64 dk][64 k] swizzled, 8KB each
  __shared__ bf16 pt[4][512];       // per-wave P tile, 1KB
  char* KbL = (char*)&Kb[0][0];
  char* VbL = (char*)&Vb[0][0];

  const bf16* qbase = qb + ((size_t)bh*S + q0 + lr)*DK + lg*8;
  bf16x8 qa0 = *(const bf16x8*)(qbase);
  bf16x8 qa1 = *(const bf16x8*)(qbase + 32);
  SFENCE();   // keep q loads out of the counted windows below

  const char* kg = (const char*)(kb + (size_t)bh*S*DK);   // 8KB contiguous per tile
  const char* vg = (const char*)(vt + (size_t)bh*DK*S);   // rows 2048B apart
  const unsigned char* mrow = mask + ((size_t)b*S + q0 + lr)*S;
  float* abase = attn + ((size_t)bh*S + q0 + lr)*S;

  // staging sources (per-lane); LDS dst = wave-uniform base + lane*16
  const char* ksrc  = kg + w*2048 + lane*16;                         // + t*8192
  const char* vsrcA = vg + (size_t)(w*16 + (lane>>3))*2048 + (lane&7)*16;   // + t*128
  const char* vsrcB = vsrcA + 8*2048;
  const int ldsK = w*2048;   // + buf*8192

  // fragment read offsets (bf16 idx), swizzle: slot ^ (row&7)
  const int krow = lr*64;
  const int kf0o = krow + ((lg ^ (lr&7))<<3);
  const int kf1o = krow + (((4+lg) ^ (lr&7))<<3);
  const int swzP = (lr & 3) << 4;

  uchar4 mkc[4], mkn[4];

  // ================= PASS 1: row sums =================
  gl16(ksrc,        KbL + ldsK);
  gl16(ksrc + 1024, KbL + ldsK + 1024);
  SFENCE();
  #pragma unroll
  for (int i=0;i<4;++i) mkn[i] = *(const uchar4*)(mrow + i*16 + lg*4);
  SFENCE();
  WAITV(4);
  BARRIER();
  SFENCE();

  float sum = 0.f;
  for (int t = 0; t < 16; ++t) {
    const bf16* Kc = (const bf16*)(KbL + (t&1)*8192);
    if (t < 15) {
      gl16(ksrc + (t+1)*8192,        KbL + ((t+1)&1)*8192 + ldsK);
      gl16(ksrc + (t+1)*8192 + 1024, KbL + ((t+1)&1)*8192 + ldsK + 1024);
    }
    SFENCE();
    #pragma unroll
    for (int i=0;i<4;++i) mkc[i] = mkn[i];
    if (t < 15) {
      #pragma unroll
      for (int i=0;i<4;++i) mkn[i] = *(const uchar4*)(mrow + (t+1)*64 + i*16 + lg*4);
    }
    __builtin_amdgcn_s_setprio(1);
    #pragma unroll
    for (int i=0;i<4;++i) {
      bf16x8 kf0 = *(const bf16x8*)&Kc[i*1024 + kf0o];
      bf16x8 kf1 = *(const bf16x8*)&Kc[i*1024 + kf1o];
      f32x4 sc = {0.f,0.f,0.f,0.f};
      sc = MFMA(kf0, qa0, sc, 0,0,0);
      sc = MFMA(kf1, qa1, sc, 0,0,0);
      sum += mkc[i].x ? 0.f : __expf(sc[0]*0.125f);
      sum += mkc[i].y ? 0.f : __expf(sc[1]*0.125f);
      sum += mkc[i].z ? 0.f : __expf(sc[2]*0.125f);
      sum += mkc[i].w ? 0.f : __expf(sc[3]*0.125f);
    }
    __builtin_amdgcn_s_setprio(0);
    SFENCE();
    if (t < 15) {
      WAITV(4);
      BARRIER();
      SFENCE();
    }
  }
  sum += __shfl_xor(sum, 16);
  sum += __shfl_xor(sum, 32);
  float inv = 1.f / sum;

  // ================= PASS 2: attn write + PV =================
  f32x4 cacc[4];
  #pragma unroll
  for (int d=0;d<4;++d) cacc[d] = (f32x4){0.f,0.f,0.f,0.f};

  // prologue (Kb[0] free: pass1 t=15 read Kb[1]; Vb untouched)
  gl16(ksrc,        KbL + ldsK);
  gl16(ksrc + 1024, KbL + ldsK + 1024);
  gl16(vsrcA,       VbL + ldsK);
  gl16(vsrcB,       VbL + ldsK + 1024);
  SFENCE();
  #pragma unroll
  for (int i=0;i<4;++i) mkn[i] = *(const uchar4*)(mrow + i*16 + lg*4);
  SFENCE();
  WAITV(4);
  BARRIER();
  SFENCE();

  for (int t = 0; t < 16; ++t) {
    const bf16* Kc = (const bf16*)(KbL + (t&1)*8192);
    const bf16* Vc = (const bf16*)(VbL + (t&1)*8192);
    if (t < 15) {
      gl16(ksrc + (t+1)*8192,        KbL + ((t+1)&1)*8192 + ldsK);
      gl16(ksrc + (t+1)*8192 + 1024, KbL + ((t+1)&1)*8192 + ldsK + 1024);
      gl16(vsrcA + (t+1)*128,        VbL + ((t+1)&1)*8192 + ldsK);
      gl16(vsrcB + (t+1)*128,        VbL + ((t+1)&1)*8192 + ldsK + 1024);
    }
    SFENCE();
    #pragma unroll
    for (int i=0;i<4;++i) mkc[i] = mkn[i];
    if (t < 15) {
      #pragma unroll
      for (int i=0;i<4;++i) mkn[i] = *(const uchar4*)(mrow + (t+1)*64 + i*16 + lg*4);
    }
    char* buf = (char*)&pt[w][0];
    __builtin_amdgcn_s_setprio(1);
    #pragma unroll
    for (int u = 0; u < 2; ++u) {
      #pragma unroll
      for (int half = 0; half < 2; ++half) {
        int i = u*2 + half;
        bf16x8 kf0 = *(const bf16x8*)&Kc[i*1024 + kf0o];
        bf16x8 kf1 = *(const bf16x8*)&Kc[i*1024 + kf1o];
        f32x4 sc = {0.f,0.f,0.f,0.f};
        sc = MFMA(kf0, qa0, sc, 0,0,0);
        sc = MFMA(kf1, qa1, sc, 0,0,0);
        float p0 = mkc[i].x ? 0.f : __expf(sc[0]*0.125f)*inv;
        float p1 = mkc[i].y ? 0.f : __expf(sc[1]*0.125f)*inv;
        float p2 = mkc[i].z ? 0.f : __expf(sc[2]*0.125f)*inv;
        float p3 = mkc[i].w ? 0.f : __expf(sc[3]*0.125f)*inv;
        *(float4*)(abase + t*64 + i*16 + lg*4) = (float4){p0,p1,p2,p3};
        uint2 pw2; pw2.x = pk2(p0,p1); pw2.y = pk2(p2,p3);
        *(uint2*)(buf + lr*64 + ((half*32 + lg*8) ^ swzP)) = pw2;
      }
      bf16x8 pa = *(const bf16x8*)(buf + lr*64 + ((lg*16) ^ swzP));
      #pragma unroll
      for (int dd=0; dd<4; ++dd) {
        bf16x8 vf = *(const bf16x8*)&Vc[dd*1024 + lr*64 + ((((u*4+lg) ^ (lr&7)))<<3)];
        cacc[dd] = MFMA(pa, vf, cacc[dd], 0,0,0);
      }
    }
    __builtin_amdgcn_s_setprio(0);
    SFENCE();
    if (t < 15) {
      WAITV(8);
      BARRIER();
      SFENCE();
    }
  }

  // ---- ctx write: lane holds ctx[q=q0+lg*4+r][d*16+lr]
  #pragma unroll
  for (int d=0;d<4;++d)
    #pragma unroll
    for (int r=0;r<4;++r)
      ctx[((size_t)b*S + q0 + lg*4 + r)*DM + h*DK + d*16 + lr] = (bf16)cacc[d][r];
}

// ---------------- layernorm rows of 768 -> d_out
__global__ void k_ln(const float* __restrict__ x, const float* __restrict__ gamma,
                     const float* __restrict__ beta, float* __restrict__ out) {
  int row = blockIdx.x; int tid = threadIdx.x;
  const float* xr = x + (size_t)row*DM;
  float v0 = xr[tid], v1 = xr[tid+256], v2 = xr[tid+512];
  float s = v0+v1+v2, ss = v0*v0+v1*v1+v2*v2;
  #pragma unroll
  for (int off=32; off; off>>=1){ s += __shfl_xor(s,off); ss += __shfl_xor(ss,off); }
  __shared__ float sm[8];
  int w = tid>>6;
  if ((tid&63)==0){ sm[w]=s; sm[4+w]=ss; }
  __syncthreads();
  s = sm[0]+sm[1]+sm[2]+sm[3]; ss = sm[4]+sm[5]+sm[6]+sm[7];
  float mean = s * (1.f/DM);
  float var = ss * (1.f/DM) - mean*mean;
  float rstd = rsqrtf(var + 1e-5f);
  out[(size_t)row*DM + tid]     = (v0-mean)*rstd*gamma[tid]     + beta[tid];
  out[(size_t)row*DM + tid+256] = (v1-mean)*rstd*gamma[tid+256] + beta[tid+256];
  out[(size_t)row*DM + tid+512] = (v2-mean)*rstd*gamma[tid+512] + beta[tid+512];
}

extern "C" void kernel_launch(void* const* d_in, const int* in_sizes, int n_in,
                              void* d_out, int out_size, void* d_ws, size_t ws_size,
                              hipStream_t stream) {
  const float* Q  = (const float*)d_in[0];
  const float* K  = (const float*)d_in[1];
  const float* V  = (const float*)d_in[2];
  const unsigned char* mask = (const unsigned char*)d_in[3];
  const float* Wq = (const float*)d_in[4];
  const float* bq = (const float*)d_in[5];
  const float* Wk = (const float*)d_in[6];
  const float* bk = (const float*)d_in[7];
  const float* Wv = (const float*)d_in[8];
  const float* bv = (const float*)d_in[9];
  const float* Wo = (const float*)d_in[10];
  const float* bo = (const float*)d_in[11];
  const float* gamma = (const float*)d_in[12];
  const float* beta  = (const float*)d_in[13];

  char* ws = (char*)d_ws;
  bf16* wt  = (bf16*)(ws + 0);            // [4][768][768]        4,718,592 B
  bf16* xb  = (bf16*)(ws + 4718592);      // [3][6144][768]      28,311,552 B
  bf16* qb  = (bf16*)(ws + 33030144);     // [72][1024][64]       9,437,184 B
  bf16* kb  = (bf16*)(ws + 42467328);     // [72][1024][64] swz   9,437,184 B
  bf16* vt  = (bf16*)(ws + 51904512);     // [72][64][1024] swz   9,437,184 B
  bf16* ctx = (bf16*)(ws + 61341696);     // [6][1024][768]       9,437,184 B
  float* x  = (float*)(ws + 4718592);     // alias xb (dead after k_proj)

  float* out  = (float*)d_out;                   // [6][1024][768]
  float* attn = out + (size_t)B*S*DM;            // [6][12][1024][1024]

  k_prep  <<<dim3(2304,7),  256, 0, stream>>>(Q,K,V,Wq,Wk,Wv,Wo,xb,wt);
  k_proj  <<<dim3(48,6,3),  256, 0, stream>>>(xb,wt,bq,bk,bv,qb,kb,vt);
  k_fattn <<<dim3(16,BH),   256, 0, stream>>>(qb,kb,vt,mask,attn,ctx);
  k_oproj <<<dim3(48,6),    256, 0, stream>>>(ctx, wt + (size_t)3*DM*DM, bo, Q, x);
  k_ln    <<<dim3(M),       256, 0, stream>>>(x,gamma,beta,out);
}